// Round 2
// baseline (355.356 us; speedup 1.0000x reference)
//
#include <hip/hip_runtime.h>

#define B_   2
#define CIN  16
#define HIN  384
#define WIN  1280
#define CO   24
#define HQ   96
#define WL   320
#define WR   1280
#define DMAX 64

__device__ __forceinline__ float lk(float v) { return v >= 0.f ? v : 0.2f * v; }

// ---------------- em conv, left branch: 4x4 stride (4,4), VALID ----------------
__global__ __launch_bounds__(256) void k_em_left(
    const float* __restrict__ x, const float* __restrict__ w,
    const float* __restrict__ bias, float* __restrict__ out)
{
    __shared__ float sw[CO * CIN * 16];
    __shared__ float sb[CO];
    for (int i = threadIdx.x; i < CO * CIN * 16; i += 256) sw[i] = w[i];
    if (threadIdx.x < CO) sb[threadIdx.x] = bias[threadIdx.x];
    __syncthreads();

    int t = blockIdx.x * 256 + threadIdx.x;       // t < 2*96*320 = 61440
    int j = t % WL; int r = t / WL; int h = r % HQ; int b = r / HQ;

    float acc[CO];
#pragma unroll
    for (int o = 0; o < CO; ++o) acc[o] = sb[o];

    const float* xb = x + (size_t)b * CIN * HIN * WIN;
    for (int c = 0; c < CIN; ++c) {
#pragma unroll
        for (int kh = 0; kh < 4; ++kh) {
            const float4 v = *(const float4*)(xb + ((size_t)c * HIN + 4 * h + kh) * WIN + 4 * j);
#pragma unroll
            for (int o = 0; o < CO; ++o) {
                const float* wp = &sw[((o * CIN + c) * 4 + kh) * 4];
                acc[o] += v.x * wp[0] + v.y * wp[1] + v.z * wp[2] + v.w * wp[3];
            }
        }
    }
#pragma unroll
    for (int o = 0; o < CO; ++o)
        out[((size_t)(b * CO + o) * HQ + h) * WL + j] = lk(acc[o]);
}

// -------- em conv, right branch: 4x4 stride (4,1), width pad (1,2) -------------
// 2 output pixels per thread: j0 and j0+640
__global__ __launch_bounds__(256) void k_em_right(
    const float* __restrict__ x, const float* __restrict__ w,
    const float* __restrict__ bias, float* __restrict__ out)
{
    __shared__ float sw[CO * CIN * 16];
    __shared__ float sb[CO];
    for (int i = threadIdx.x; i < CO * CIN * 16; i += 256) sw[i] = w[i];
    if (threadIdx.x < CO) sb[threadIdx.x] = bias[threadIdx.x];
    __syncthreads();

    int t = blockIdx.x * 256 + threadIdx.x;       // t < 2*96*640 = 122880
    int j0 = t % 640; int r = t / 640; int h = r % HQ; int b = r / HQ;

    float acc0[CO], acc1[CO];
#pragma unroll
    for (int o = 0; o < CO; ++o) { acc0[o] = sb[o]; acc1[o] = sb[o]; }

    const float* xb = x + (size_t)b * CIN * HIN * WIN;
    for (int c = 0; c < CIN; ++c) {
#pragma unroll
        for (int kh = 0; kh < 4; ++kh) {
            const float* xr = xb + ((size_t)c * HIN + 4 * h + kh) * WIN;
            float a0[4], a1[4];
#pragma unroll
            for (int kw = 0; kw < 4; ++kw) {
                int col0 = j0 + kw - 1;             // can be -1 only when j0==0
                int col1 = j0 + 640 + kw - 1;       // can be >=1280 at the right edge
                a0[kw] = (col0 >= 0)  ? xr[col0] : 0.f;
                a1[kw] = (col1 < WIN) ? xr[col1] : 0.f;
            }
#pragma unroll
            for (int o = 0; o < CO; ++o) {
                const float* wp = &sw[((o * CIN + c) * 4 + kh) * 4];
                acc0[o] += a0[0] * wp[0] + a0[1] * wp[1] + a0[2] * wp[2] + a0[3] * wp[3];
                acc1[o] += a1[0] * wp[0] + a1[1] * wp[1] + a1[2] * wp[2] + a1[3] * wp[3];
            }
        }
    }
#pragma unroll
    for (int o = 0; o < CO; ++o) {
        size_t base = ((size_t)(b * CO + o) * HQ + h) * WR;
        out[base + j0]       = lk(acc0[o]);
        out[base + j0 + 640] = lk(acc1[o]);
    }
}

// ---------------- 1x1 rc conv (24->24), leaky, in-place -----------------------
__global__ __launch_bounds__(256) void k_rc(
    const float* __restrict__ w, const float* __restrict__ bias,
    float* __restrict__ buf, int Wq)
{
    __shared__ float sw[CO * CO];
    __shared__ float sb[CO];
    for (int i = threadIdx.x; i < CO * CO; i += 256) sw[i] = w[i];
    if (threadIdx.x < CO) sb[threadIdx.x] = bias[threadIdx.x];
    __syncthreads();

    int t = blockIdx.x * 256 + threadIdx.x;
    int j = t % Wq; int r = t / Wq; int h = r % HQ; int b = r / HQ;
    size_t base = ((size_t)b * CO * HQ + h) * Wq + j;
    size_t cs = (size_t)HQ * Wq;

    float in[CO];
#pragma unroll
    for (int c = 0; c < CO; ++c) in[c] = buf[base + c * cs];
    float ov[CO];
#pragma unroll
    for (int o = 0; o < CO; ++o) {
        float a = sb[o];
#pragma unroll
        for (int c = 0; c < CO; ++c) a += in[c] * sw[o * CO + c];
        ov[o] = lk(a);
    }
#pragma unroll
    for (int o = 0; o < CO; ++o) buf[base + o * cs] = ov[o];
}

// ------- fused: cost volume + min/argmin + tf 1x1 conv + output assembly ------
__global__ __launch_bounds__(256) void k_cost(
    const float* __restrict__ fl, const float* __restrict__ fr,
    const float* __restrict__ wtf, const float* __restrict__ btf,
    float* __restrict__ out, float* __restrict__ cost)
{
    __shared__ float swt[13 * 25];
    __shared__ float sbt[13];
    for (int i = threadIdx.x; i < 13 * 25; i += 256) swt[i] = wtf[i];
    if (threadIdx.x < 13) sbt[threadIdx.x] = btf[threadIdx.x];
    __syncthreads();

    int t = blockIdx.x * 256 + threadIdx.x;       // t < 2*96*320
    int j = t % WL; int r = t / WL; int h = r % HQ; int b = r / HQ;

    float flv[CO];
    size_t lbase = ((size_t)b * CO * HQ + h) * WL + j;
    size_t lcs = (size_t)HQ * WL;
#pragma unroll
    for (int c = 0; c < CO; ++c) flv[c] = fl[lbase + c * lcs];

    const float* frRow = fr + ((size_t)b * CO * HQ + h) * WR;
    const size_t rcs = (size_t)HQ * WR;
    size_t cbase = ((size_t)b * DMAX * HQ + h) * WL + j;

    float best = 3.4e38f; int bd = 0;
    for (int d = 0; d < DMAX; d += 4) {
        int base = 4 * j + 1 - d;                 // gather idx (max 1277, so no upper clip)
        float c0 = 0.f, c1 = 0.f, c2 = 0.f, c3 = 0.f;
        if (base >= 3) {
#pragma unroll
            for (int c = 0; c < CO; ++c) {
                const float* pc = frRow + c * rcs + (base - 3);
                float f3 = pc[0], f2 = pc[1], f1 = pc[2], f0 = pc[3];
                c0 += fabsf(flv[c] - f0);
                c1 += fabsf(flv[c] - f1);
                c2 += fabsf(flv[c] - f2);
                c3 += fabsf(flv[c] - f3);
            }
        } else {
            int i0 = max(base, 0), i1 = max(base - 1, 0), i2 = max(base - 2, 0), i3 = max(base - 3, 0);
#pragma unroll
            for (int c = 0; c < CO; ++c) {
                const float* pc = frRow + c * rcs;
                c0 += fabsf(flv[c] - pc[i0]);
                c1 += fabsf(flv[c] - pc[i1]);
                c2 += fabsf(flv[c] - pc[i2]);
                c3 += fabsf(flv[c] - pc[i3]);
            }
        }
        // first-occurrence argmin, ascending d (matches jnp.argmin; clipped-region
        // ties are bitwise-equal because the summation order over c is identical)
        if (c0 < best) { best = c0; bd = d; }
        if (c1 < best) { best = c1; bd = d + 1; }
        if (c2 < best) { best = c2; bd = d + 2; }
        if (c3 < best) { best = c3; bd = d + 3; }

        size_t cb = cbase + (size_t)d * (HQ * WL);
        cost[cb]                 = c0;
        cost[cb + 1 * (HQ * WL)] = c1;
        cost[cb + 2 * (HQ * WL)] = c2;
        cost[cb + 3 * (HQ * WL)] = c3;
    }

    // tf 1x1 conv: 25 -> 13, input = [cost_f, fl...]
#pragma unroll
    for (int o = 0; o < 13; ++o) {
        float a = sbt[o] + swt[o * 25] * best;
#pragma unroll
        for (int c = 0; c < CO; ++c) a += swt[o * 25 + 1 + c] * flv[c];
        out[((size_t)(b * 16 + 3 + o) * HQ + h) * WL + j] = lk(a);
    }
    out[((size_t)(b * 16 + 0) * HQ + h) * WL + j] = (float)bd;
    out[((size_t)(b * 16 + 1) * HQ + h) * WL + j] = 0.f;
    out[((size_t)(b * 16 + 2) * HQ + h) * WL + j] = 0.f;
}

extern "C" void kernel_launch(void* const* d_in, const int* in_sizes, int n_in,
                              void* d_out, int out_size, void* d_ws, size_t ws_size,
                              hipStream_t stream) {
    const float* fl_in = (const float*)d_in[0];
    const float* fr_in = (const float*)d_in[1];
    // d_in[2] = max_disp (int scalar) -- fixed at 64, unused
    const float* w_em = (const float*)d_in[3];
    const float* b_em = (const float*)d_in[4];
    const float* w_rc = (const float*)d_in[5];
    const float* b_rc = (const float*)d_in[6];
    const float* w_tf = (const float*)d_in[7];
    const float* b_tf = (const float*)d_in[8];

    float* out  = (float*)d_out;
    float* cost = out + (size_t)B_ * 16 * HQ * WL;             // 983040 floats offset

    float* fl_ws = (float*)d_ws;                               // [2,24,96,320]  f32
    float* fr_ws = fl_ws + (size_t)B_ * CO * HQ * WL;          // [2,24,96,1280] f32

    hipLaunchKernelGGL(k_em_left,  dim3(240), dim3(256), 0, stream, fl_in, w_em, b_em, fl_ws);
    hipLaunchKernelGGL(k_em_right, dim3(480), dim3(256), 0, stream, fr_in, w_em, b_em, fr_ws);
    hipLaunchKernelGGL(k_rc,       dim3(240), dim3(256), 0, stream, w_rc, b_rc, fl_ws, WL);
    hipLaunchKernelGGL(k_rc,       dim3(960), dim3(256), 0, stream, w_rc, b_rc, fr_ws, WR);
    hipLaunchKernelGGL(k_cost,     dim3(240), dim3(256), 0, stream, fl_ws, fr_ws, w_tf, b_tf, out, cost);
}

// Round 4
// 277.989 us; speedup vs baseline: 1.2783x; 1.2783x over previous
//
#include <hip/hip_runtime.h>

#define B_   2
#define CIN  16
#define HIN  384
#define WIN  1280
#define CO   24
#define HQ   96
#define WL   320
#define WR   1280
#define DMAX 64

__device__ __forceinline__ float lk(float v) { return v >= 0.f ? v : 0.2f * v; }

// ============ Kernel A: em_left (4x4 s4,4 VALID) + leaky + rc 1x1 + leaky ====
// block 256 = 128 px * 2 o-halves (12 out-ch each); grid 480
__global__ __launch_bounds__(256) void k_left(
    const float* __restrict__ x, const float* __restrict__ w_em,
    const float* __restrict__ b_em, const float* __restrict__ w_rc,
    const float* __restrict__ b_rc, float* __restrict__ out)
{
    __shared__ float sw[CO * CIN * 16];   // em weights [o][c][kh][kw]
    __shared__ float swt[CO * CO];        // rc weights transposed [c][o]
    __shared__ float sbe[CO], sbr[CO];
    __shared__ float em[CO * 128];        // em result [o][px]

    for (int i = threadIdx.x; i < CO * CIN * 16; i += 256) sw[i] = w_em[i];
    for (int i = threadIdx.x; i < CO * CO; i += 256) swt[i] = w_rc[(i % CO) * CO + (i / CO)];
    if (threadIdx.x < CO) { sbe[threadIdx.x] = b_em[threadIdx.x]; sbr[threadIdx.x] = b_rc[threadIdx.x]; }
    __syncthreads();

    const int t = threadIdx.x;
    const int half = t >> 7, pxl = t & 127;
    const int obase = half * 12;
    const int flat = blockIdx.x * 128 + pxl;       // < 61440
    const int j = flat % WL, h = (flat / WL) % HQ, b = flat / (WL * HQ);

    float acc[12];
#pragma unroll
    for (int oo = 0; oo < 12; ++oo) acc[oo] = sbe[obase + oo];

    for (int c = 0; c < CIN; ++c) {
#pragma unroll
        for (int kh = 0; kh < 4; ++kh) {
            const float4 v = *(const float4*)(x + ((size_t)(b * CIN + c) * HIN + 4 * h + kh) * WIN + 4 * j);
#pragma unroll
            for (int oo = 0; oo < 12; ++oo) {
                const float4 wv = *(const float4*)&sw[(((obase + oo) * CIN + c) * 4 + kh) * 4];
                acc[oo] += v.x * wv.x + v.y * wv.y + v.z * wv.z + v.w * wv.w;
            }
        }
    }
#pragma unroll
    for (int oo = 0; oo < 12; ++oo) em[(obase + oo) * 128 + pxl] = lk(acc[oo]);
    __syncthreads();

    // rc phase: same thread mapping (px, o-half)
    float acc2[12];
#pragma unroll
    for (int oo = 0; oo < 12; ++oo) acc2[oo] = sbr[obase + oo];
    for (int c = 0; c < CO; ++c) {
        const float in_c = em[c * 128 + pxl];
#pragma unroll
        for (int oo = 0; oo < 12; ++oo) acc2[oo] += in_c * swt[c * CO + obase + oo];
    }
#pragma unroll
    for (int oo = 0; oo < 12; ++oo)
        out[((size_t)(b * CO + obase + oo) * HQ + h) * WL + j] = lk(acc2[oo]);
}

// ======= Kernel B: em_right (4x4 s4,1 pad 1,2) + leaky + rc 1x1 + leaky ======
// block 256 = 64 lanes (4 adjacent px each) * 4 o-quarters (6 out-ch each)
// block covers 256 consecutive px of one row; grid 960
__global__ __launch_bounds__(256) void k_right(
    const float* __restrict__ x, const float* __restrict__ w_em,
    const float* __restrict__ b_em, const float* __restrict__ w_rc,
    const float* __restrict__ b_rc, float* __restrict__ out)
{
    __shared__ float sw[CO * CIN * 16];
    __shared__ float swt[CO * CO];        // rc transposed [c][o]
    __shared__ float sbe[CO], sbr[CO];
    __shared__ float em[CO * 256];        // [o][px]

    for (int i = threadIdx.x; i < CO * CIN * 16; i += 256) sw[i] = w_em[i];
    for (int i = threadIdx.x; i < CO * CO; i += 256) swt[i] = w_rc[(i % CO) * CO + (i / CO)];
    if (threadIdx.x < CO) { sbe[threadIdx.x] = b_em[threadIdx.x]; sbr[threadIdx.x] = b_rc[threadIdx.x]; }
    __syncthreads();

    const int t = threadIdx.x;
    const int L = t & 63, quarter = t >> 6;
    const int obase = quarter * 6;
    const int row = blockIdx.x / 5, jbase = (blockIdx.x % 5) * 256;
    const int b = row / HQ, h = row % HQ;

    // Boundary guards. NOTE: local index 4L-1 may be -1 -> reads global col
    // jbase-1, which is VALID whenever vm1 (only jbase==0,L==0 is true padding).
    // This was the R3 bug: clamping -1 to 0 corrupted columns 256/512/768/1024.
    const bool vm1 = (jbase + 4 * L - 1) >= 0;
    const bool vp4 = (jbase + 4 * L + 4) < WIN;
    const bool vp5 = (jbase + 4 * L + 5) < WIN;
    const int  im1 = 4 * L - 1;
    const int  ip4 = 4 * L + 4;
    const int  ip5 = 4 * L + 5;

    float acc[4][6];
#pragma unroll
    for (int k = 0; k < 4; ++k)
#pragma unroll
        for (int oo = 0; oo < 6; ++oo) acc[k][oo] = sbe[obase + oo];

    for (int c = 0; c < CIN; ++c) {
#pragma unroll
        for (int kh = 0; kh < 4; ++kh) {
            const float* xr = x + ((size_t)(b * CIN + c) * HIN + 4 * h + kh) * WIN + jbase;
            const float4 v = *(const float4*)(xr + 4 * L);
            float in[7];
            in[0] = vm1 ? xr[im1] : 0.f;
            in[1] = v.x; in[2] = v.y; in[3] = v.z; in[4] = v.w;
            in[5] = vp4 ? xr[ip4] : 0.f;
            in[6] = vp5 ? xr[ip5] : 0.f;
#pragma unroll
            for (int oo = 0; oo < 6; ++oo) {
                const float4 wv = *(const float4*)&sw[(((obase + oo) * CIN + c) * 4 + kh) * 4];
#pragma unroll
                for (int k = 0; k < 4; ++k)
                    acc[k][oo] += in[k] * wv.x + in[k + 1] * wv.y + in[k + 2] * wv.z + in[k + 3] * wv.w;
            }
        }
    }
#pragma unroll
    for (int oo = 0; oo < 6; ++oo) {
        float4 st = make_float4(lk(acc[0][oo]), lk(acc[1][oo]), lk(acc[2][oo]), lk(acc[3][oo]));
        *(float4*)&em[(obase + oo) * 256 + 4 * L] = st;
    }
    __syncthreads();

    // rc phase: thread <-> px 1:1 (256 px)
    float acc2[CO];
#pragma unroll
    for (int o = 0; o < CO; ++o) acc2[o] = sbr[o];
    for (int c = 0; c < CO; ++c) {
        const float in_c = em[c * 256 + t];
#pragma unroll
        for (int o = 0; o < CO; ++o) acc2[o] += in_c * swt[c * CO + o];
    }
#pragma unroll
    for (int o = 0; o < CO; ++o)
        out[((size_t)(b * CO + o) * HQ + h) * WR + jbase + t] = lk(acc2[o]);
}

// ====== Kernel C: cost volume + min/argmin + tf 1x1 + output assembly ========
// block 320 threads (thread <-> output col j), one block per (b,h); grid 192.
// fr rows staged in LDS, phase-permuted: padded col cp = col+64 (cp in [0,1344));
// addr = ((cp&3)*12 + c)*337 + (cp>>2). cp 1..63 hold replicated fr[c][0]
// (the clip-to-0 region), so no clamping in the inner loop; fixed-phase d-steps
// read consecutive LDS addresses (conflict-free, imm-offset ds_reads).
__global__ __launch_bounds__(320) void k_cost(
    const float* __restrict__ fl, const float* __restrict__ fr,
    const float* __restrict__ wtf, const float* __restrict__ btf,
    float* __restrict__ out, float* __restrict__ cost)
{
    __shared__ float frs[4 * 12 * 337];   // 64704 B

    const int j = threadIdx.x;            // 0..319
    const int b = blockIdx.x / HQ, h = blockIdx.x % HQ;

    float acc[DMAX];
#pragma unroll
    for (int d = 0; d < DMAX; ++d) acc[d] = 0.f;

    for (int ch = 0; ch < 2; ++ch) {
        const int c0 = ch * 12;
        __syncthreads();
        for (int c = 0; c < 12; ++c) {
            const float* frow = fr + ((size_t)(b * CO + c0 + c) * HQ + h) * WR;
            const float4 v = *(const float4*)(frow + 4 * j);   // cols 4j..4j+3 -> cp 4(j+16)+p
            frs[(0 * 12 + c) * 337 + j + 16] = v.x;
            frs[(1 * 12 + c) * 337 + j + 16] = v.y;
            frs[(2 * 12 + c) * 337 + j + 16] = v.z;
            frs[(3 * 12 + c) * 337 + j + 16] = v.w;
            if (j >= 1 && j < 64)                               // left pad cp = j
                frs[((j & 3) * 12 + c) * 337 + (j >> 2)] = frow[0];
        }
        __syncthreads();

        for (int c = 0; c < 12; ++c) {
            const float flc = fl[((size_t)(b * CO + c0 + c) * HQ + h) * WL + j];
#pragma unroll
            for (int p = 0; p < 4; ++p) {
                const int dp0 = (1 - p) & 3;                    // d residue for this phase
                const int q0 = j + ((65 - dp0) >> 2);           // q at i=0; q = q0 - i
                const int abase = (p * 12 + c) * 337 + q0;
#pragma unroll
                for (int i = 0; i < 16; ++i) {
                    const float v = frs[abase - i];
                    acc[dp0 + 4 * i] += fabsf(flc - v);
                }
            }
        }
    }

    // min / first-occurrence argmin, ascending d
    float best = acc[0]; int bd = 0;
#pragma unroll
    for (int d = 1; d < DMAX; ++d)
        if (acc[d] < best) { best = acc[d]; bd = d; }

    // cost volume out [B,D,H,WL]
    const size_t cbase = ((size_t)b * DMAX * HQ + h) * WL + j;
#pragma unroll
    for (int d = 0; d < DMAX; ++d)
        cost[cbase + (size_t)d * (HQ * WL)] = acc[d];

    // reload fl pixel vector for tf conv
    float flr[CO];
#pragma unroll
    for (int c = 0; c < CO; ++c) flr[c] = fl[((size_t)(b * CO + c) * HQ + h) * WL + j];

#pragma unroll
    for (int o = 0; o < 13; ++o) {
        float a = btf[o] + wtf[o * 25] * best;
#pragma unroll
        for (int c = 0; c < CO; ++c) a += wtf[o * 25 + 1 + c] * flr[c];
        out[((size_t)(b * 16 + 3 + o) * HQ + h) * WL + j] = lk(a);
    }
    out[((size_t)(b * 16 + 0) * HQ + h) * WL + j] = (float)bd;
    out[((size_t)(b * 16 + 1) * HQ + h) * WL + j] = 0.f;
    out[((size_t)(b * 16 + 2) * HQ + h) * WL + j] = 0.f;
}

extern "C" void kernel_launch(void* const* d_in, const int* in_sizes, int n_in,
                              void* d_out, int out_size, void* d_ws, size_t ws_size,
                              hipStream_t stream) {
    const float* fl_in = (const float*)d_in[0];
    const float* fr_in = (const float*)d_in[1];
    // d_in[2] = max_disp (int) -- fixed 64
    const float* w_em = (const float*)d_in[3];
    const float* b_em = (const float*)d_in[4];
    const float* w_rc = (const float*)d_in[5];
    const float* b_rc = (const float*)d_in[6];
    const float* w_tf = (const float*)d_in[7];
    const float* b_tf = (const float*)d_in[8];

    float* out  = (float*)d_out;
    float* cost = out + (size_t)B_ * 16 * HQ * WL;

    float* fl_ws = (float*)d_ws;                               // [2,24,96,320]
    float* fr_ws = fl_ws + (size_t)B_ * CO * HQ * WL;          // [2,24,96,1280]

    hipLaunchKernelGGL(k_left,  dim3(480), dim3(256), 0, stream,
                       fl_in, w_em, b_em, w_rc, b_rc, fl_ws);
    hipLaunchKernelGGL(k_right, dim3(960), dim3(256), 0, stream,
                       fr_in, w_em, b_em, w_rc, b_rc, fr_ws);
    hipLaunchKernelGGL(k_cost,  dim3(192), dim3(320), 0, stream,
                       fl_ws, fr_ws, w_tf, b_tf, out, cost);
}

// Round 5
// 269.260 us; speedup vs baseline: 1.3197x; 1.0324x over previous
//
#include <hip/hip_runtime.h>

#define B_   2
#define CIN  16
#define HIN  384
#define WIN  1280
#define CO   24
#define HQ   96
#define WL   320
#define WR   1280
#define DMAX 64

__device__ __forceinline__ float lk(float v) { return v >= 0.f ? v : 0.2f * v; }

// ============ Kernel A: em_left (4x4 s4,4 VALID) + leaky + rc 1x1 + leaky ====
// block 256 = 128 px * 2 o-halves (12 out-ch each); grid 480
// smem union: [0,6144) = em weights during conv, then em activations (3072 used)
__global__ __launch_bounds__(256) void k_left(
    const float* __restrict__ x, const float* __restrict__ w_em,
    const float* __restrict__ b_em, const float* __restrict__ w_rc,
    const float* __restrict__ b_rc, float* __restrict__ out)
{
    __shared__ float smem[CO * CIN * 16];  // sw -> em (union), 24 KB
    __shared__ float swt[CO * CO];         // rc weights transposed [c][o]
    __shared__ float sbe[CO], sbr[CO];

    for (int i = threadIdx.x; i < CO * CIN * 16; i += 256) smem[i] = w_em[i];
    for (int i = threadIdx.x; i < CO * CO; i += 256) swt[i] = w_rc[(i % CO) * CO + (i / CO)];
    if (threadIdx.x < CO) { sbe[threadIdx.x] = b_em[threadIdx.x]; sbr[threadIdx.x] = b_rc[threadIdx.x]; }
    __syncthreads();

    const int t = threadIdx.x;
    const int half = t >> 7, pxl = t & 127;
    const int obase = half * 12;
    const int flat = blockIdx.x * 128 + pxl;       // < 61440
    const int j = flat % WL, h = (flat / WL) % HQ, b = flat / (WL * HQ);

    float acc[12];
#pragma unroll
    for (int oo = 0; oo < 12; ++oo) acc[oo] = sbe[obase + oo];

    for (int c = 0; c < CIN; ++c) {
#pragma unroll
        for (int kh = 0; kh < 4; ++kh) {
            const float4 v = *(const float4*)(x + ((size_t)(b * CIN + c) * HIN + 4 * h + kh) * WIN + 4 * j);
#pragma unroll
            for (int oo = 0; oo < 12; ++oo) {
                const float4 wv = *(const float4*)&smem[(((obase + oo) * CIN + c) * 4 + kh) * 4];
                acc[oo] += v.x * wv.x + v.y * wv.y + v.z * wv.z + v.w * wv.w;
            }
        }
    }
    __syncthreads();                       // all reads of sw done before overlay
#pragma unroll
    for (int oo = 0; oo < 12; ++oo) smem[(obase + oo) * 128 + pxl] = lk(acc[oo]);
    __syncthreads();

    // rc phase: same thread mapping (px, o-half)
    float acc2[12];
#pragma unroll
    for (int oo = 0; oo < 12; ++oo) acc2[oo] = sbr[obase + oo];
    for (int c = 0; c < CO; ++c) {
        const float in_c = smem[c * 128 + pxl];
#pragma unroll
        for (int oo = 0; oo < 12; ++oo) acc2[oo] += in_c * swt[c * CO + obase + oo];
    }
#pragma unroll
    for (int oo = 0; oo < 12; ++oo)
        out[((size_t)(b * CO + obase + oo) * HQ + h) * WL + j] = lk(acc2[oo]);
}

// ======= Kernel B: em_right (4x4 s4,1 pad 1,2) + leaky + rc 1x1 + leaky ======
// block 256 = 64 lanes (4 adjacent px each) * 4 o-quarters (6 out-ch each)
// block covers 256 consecutive px of one row; grid 960
// smem union: [0,6144) = em weights during conv, then em activations
__global__ __launch_bounds__(256) void k_right(
    const float* __restrict__ x, const float* __restrict__ w_em,
    const float* __restrict__ b_em, const float* __restrict__ w_rc,
    const float* __restrict__ b_rc, float* __restrict__ out)
{
    __shared__ float smem[CO * CIN * 16];  // sw -> em (union), 24 KB
    __shared__ float swt[CO * CO];         // rc transposed [c][o]
    __shared__ float sbe[CO], sbr[CO];

    for (int i = threadIdx.x; i < CO * CIN * 16; i += 256) smem[i] = w_em[i];
    for (int i = threadIdx.x; i < CO * CO; i += 256) swt[i] = w_rc[(i % CO) * CO + (i / CO)];
    if (threadIdx.x < CO) { sbe[threadIdx.x] = b_em[threadIdx.x]; sbr[threadIdx.x] = b_rc[threadIdx.x]; }
    __syncthreads();

    const int t = threadIdx.x;
    const int L = t & 63, quarter = t >> 6;
    const int obase = quarter * 6;
    const int row = blockIdx.x / 5, jbase = (blockIdx.x % 5) * 256;
    const int b = row / HQ, h = row % HQ;

    // local index 4L-1 may be -1 -> reads global col jbase-1, VALID whenever vm1
    const bool vm1 = (jbase + 4 * L - 1) >= 0;
    const bool vp4 = (jbase + 4 * L + 4) < WIN;
    const bool vp5 = (jbase + 4 * L + 5) < WIN;
    const int  im1 = 4 * L - 1;
    const int  ip4 = 4 * L + 4;
    const int  ip5 = 4 * L + 5;

    float acc[4][6];
#pragma unroll
    for (int k = 0; k < 4; ++k)
#pragma unroll
        for (int oo = 0; oo < 6; ++oo) acc[k][oo] = sbe[obase + oo];

    for (int c = 0; c < CIN; ++c) {
#pragma unroll
        for (int kh = 0; kh < 4; ++kh) {
            const float* xr = x + ((size_t)(b * CIN + c) * HIN + 4 * h + kh) * WIN + jbase;
            const float4 v = *(const float4*)(xr + 4 * L);
            float in[7];
            in[0] = vm1 ? xr[im1] : 0.f;
            in[1] = v.x; in[2] = v.y; in[3] = v.z; in[4] = v.w;
            in[5] = vp4 ? xr[ip4] : 0.f;
            in[6] = vp5 ? xr[ip5] : 0.f;
#pragma unroll
            for (int oo = 0; oo < 6; ++oo) {
                const float4 wv = *(const float4*)&smem[(((obase + oo) * CIN + c) * 4 + kh) * 4];
#pragma unroll
                for (int k = 0; k < 4; ++k)
                    acc[k][oo] += in[k] * wv.x + in[k + 1] * wv.y + in[k + 2] * wv.z + in[k + 3] * wv.w;
            }
        }
    }
    __syncthreads();                       // all reads of sw done before overlay
#pragma unroll
    for (int oo = 0; oo < 6; ++oo) {
        float4 st = make_float4(lk(acc[0][oo]), lk(acc[1][oo]), lk(acc[2][oo]), lk(acc[3][oo]));
        *(float4*)&smem[(obase + oo) * 256 + 4 * L] = st;
    }
    __syncthreads();

    // rc phase: thread <-> px 1:1 (256 px)
    float acc2[CO];
#pragma unroll
    for (int o = 0; o < CO; ++o) acc2[o] = sbr[o];
    for (int c = 0; c < CO; ++c) {
        const float in_c = smem[c * 256 + t];
#pragma unroll
        for (int o = 0; o < CO; ++o) acc2[o] += in_c * swt[c * CO + o];
    }
#pragma unroll
    for (int o = 0; o < CO; ++o)
        out[((size_t)(b * CO + o) * HQ + h) * WR + jbase + t] = lk(acc2[o]);
}

// ====== Kernel C: cost volume + min/argmin + tf 1x1 + output assembly ========
// block 256 = 64 j-cols * 4 d-quarters (16 disparities each); grid 960
// (b, h, 64-wide j-chunk). fr window staged in LDS phase-permuted:
// padded col cp = x - (4*j0 - 64), x = gather col; addr = ((cp&3)*12+c)*81 + (cp>>2).
// cp with x<0 holds replicated fr[c][0] (left clip); upper clip never fires.
// Accumulation order over channels ascending == reference (bitwise-identical
// costs -> identical argmin ties). Cross-quarter argmin combined in ascending
// dq order with strict < (first-occurrence).
__global__ __launch_bounds__(256) void k_cost(
    const float* __restrict__ fl, const float* __restrict__ fr,
    const float* __restrict__ wtf, const float* __restrict__ btf,
    float* __restrict__ out, float* __restrict__ cost)
{
    __shared__ float frs[4 * 12 * 81];    // 15552 B
    __shared__ float sbest[256];
    __shared__ int   sbd[256];

    const int t  = threadIdx.x;
    const int j  = t & 63;                 // local col
    const int dq = t >> 6;                 // d-quarter: d in [16*dq, 16*dq+16)
    const int jc = blockIdx.x % 5;
    const int r  = blockIdx.x / 5;
    const int h  = r % HQ, b = r / HQ;
    const int j0 = jc * 64;
    const int jg = j0 + j;                 // global col
    const int colbase = 4 * j0 - 64;       // global col of cp=0

    float acc[16];
#pragma unroll
    for (int dl = 0; dl < 16; ++dl) acc[dl] = 0.f;

    for (int ch = 0; ch < 2; ++ch) {
        const int c0 = ch * 12;
        __syncthreads();
        for (int idx = t; idx < 12 * 320; idx += 256) {
            const int c = idx / 320, cp = idx % 320;
            const int col = colbase + cp;
            const float v = fr[((size_t)(b * CO + c0 + c) * HQ + h) * WR + (col > 0 ? col : 0)];
            frs[((cp & 3) * 12 + c) * 81 + (cp >> 2)] = v;
        }
        __syncthreads();

        for (int c = 0; c < 12; ++c) {
            const float flc = fl[((size_t)(b * CO + c0 + c) * HQ + h) * WL + jg];
#pragma unroll
            for (int p = 0; p < 4; ++p) {
                const int dp0 = (1 - p) & 3;                 // d residue of this phase
                // d = dp0 + 16*dq + 4*i ; cp = 4*j + 65 - d ; q = cp>>2 = q0 - i
                const int q0 = j - 4 * dq + ((65 - dp0) >> 2);
                const int abase = (p * 12 + c) * 81 + q0;
#pragma unroll
                for (int i = 0; i < 4; ++i)
                    acc[dp0 + 4 * i] += fabsf(flc - frs[abase - i]);
            }
        }
    }

    // cost volume writes: d = 16*dq + dl, coalesced across lanes (jg)
    const size_t cb0 = ((size_t)(b * DMAX + 16 * dq) * HQ + h) * WL + jg;
#pragma unroll
    for (int dl = 0; dl < 16; ++dl)
        cost[cb0 + (size_t)dl * (HQ * WL)] = acc[dl];

    // per-thread min / first-occurrence argmin (ascending d within quarter)
    float best = acc[0]; int bdl = 0;
#pragma unroll
    for (int dl = 1; dl < 16; ++dl)
        if (acc[dl] < best) { best = acc[dl]; bdl = dl; }
    sbest[t] = best; sbd[t] = 16 * dq + bdl;
    __syncthreads();

    if (t < 64) {
        float cur = sbest[j]; int curd = sbd[j];
#pragma unroll
        for (int g = 1; g < 4; ++g) {
            const float v = sbest[g * 64 + j];
            if (v < cur) { cur = v; curd = sbd[g * 64 + j]; }
        }
        // tf 1x1 conv: 25 -> 13, input = [cost_f, fl...]
        float flr[CO];
#pragma unroll
        for (int c = 0; c < CO; ++c) flr[c] = fl[((size_t)(b * CO + c) * HQ + h) * WL + jg];
#pragma unroll
        for (int o = 0; o < 13; ++o) {
            float a = btf[o] + wtf[o * 25] * cur;
#pragma unroll
            for (int c = 0; c < CO; ++c) a += wtf[o * 25 + 1 + c] * flr[c];
            out[((size_t)(b * 16 + 3 + o) * HQ + h) * WL + jg] = lk(a);
        }
        out[((size_t)(b * 16 + 0) * HQ + h) * WL + jg] = (float)curd;
        out[((size_t)(b * 16 + 1) * HQ + h) * WL + jg] = 0.f;
        out[((size_t)(b * 16 + 2) * HQ + h) * WL + jg] = 0.f;
    }
}

extern "C" void kernel_launch(void* const* d_in, const int* in_sizes, int n_in,
                              void* d_out, int out_size, void* d_ws, size_t ws_size,
                              hipStream_t stream) {
    const float* fl_in = (const float*)d_in[0];
    const float* fr_in = (const float*)d_in[1];
    // d_in[2] = max_disp (int) -- fixed 64
    const float* w_em = (const float*)d_in[3];
    const float* b_em = (const float*)d_in[4];
    const float* w_rc = (const float*)d_in[5];
    const float* b_rc = (const float*)d_in[6];
    const float* w_tf = (const float*)d_in[7];
    const float* b_tf = (const float*)d_in[8];

    float* out  = (float*)d_out;
    float* cost = out + (size_t)B_ * 16 * HQ * WL;

    float* fl_ws = (float*)d_ws;                               // [2,24,96,320]
    float* fr_ws = fl_ws + (size_t)B_ * CO * HQ * WL;          // [2,24,96,1280]

    hipLaunchKernelGGL(k_left,  dim3(480), dim3(256), 0, stream,
                       fl_in, w_em, b_em, w_rc, b_rc, fl_ws);
    hipLaunchKernelGGL(k_right, dim3(960), dim3(256), 0, stream,
                       fr_in, w_em, b_em, w_rc, b_rc, fr_ws);
    hipLaunchKernelGGL(k_cost,  dim3(960), dim3(256), 0, stream,
                       fl_ws, fr_ws, w_tf, b_tf, out, cost);
}